// Round 7
// baseline (217.497 us; speedup 1.0000x reference)
//
#include <hip/hip_runtime.h>

typedef __attribute__((ext_vector_type(8))) short bf16x8;
typedef __attribute__((ext_vector_type(4))) float f32x4;
typedef unsigned short u16;
typedef unsigned int u32;

#define MFMA16(A, B, C) __builtin_amdgcn_mfma_f32_16x16x32_bf16((A), (B), (C), 0, 0, 0)

#if __has_builtin(__builtin_amdgcn_exp2f)
#define EXP2(x) __builtin_amdgcn_exp2f(x)
#else
#define EXP2(x) exp2f(x)
#endif

typedef __attribute__((address_space(3))) unsigned int lds_u32;
typedef const __attribute__((address_space(1))) unsigned int glb_u32;

__device__ __forceinline__ u16 f2bf(float f) {
  union { float f; unsigned u; } x; x.f = f;
  unsigned r = (x.u + 0x7fffu + ((x.u >> 16) & 1u)) >> 16;
  return (u16)r;
}
__device__ __forceinline__ float bf2f(u16 h) {
  union { float f; unsigned u; } x; x.u = ((unsigned)h) << 16;
  return x.f;
}

// stage a 128x64 bf16 tile (row stride ld) into contiguous LDS via
// global_load_lds width=16 (dest = wave-uniform base + lane*16)
__device__ __forceinline__ void stage_tile(const u16* src, int ld, u16* lds, int tid) {
#pragma unroll
  for (int i = 0; i < 4; i++) {
    int vv = tid + i * 256;
    const u16* gp = src + (size_t)(vv >> 3) * ld + (vv & 7) * 8;
    __builtin_amdgcn_global_load_lds((glb_u32*)gp,
        (lds_u32*)(lds + (size_t)(i * 256 + (tid & 192)) * 8), 16, 0, 0);
  }
}

// ---------------- prep kernels ----------------

__global__ __launch_bounds__(256) void cast_x_kernel(const float* __restrict__ x,
                                                     u16* __restrict__ xb, int n4) {
  int i = blockIdx.x * 256 + threadIdx.x;
  if (i >= n4) return;
  float4 v = ((const float4*)x)[i];
  ushort4 o;
  o.x = f2bf(v.x); o.y = f2bf(v.y); o.z = f2bf(v.z); o.w = f2bf(v.w);
  ((ushort4*)xb)[i] = o;
}

// W_attn [512][1536] -> wta [1536][512] bf16, tiled 64x64 transpose
__global__ __launch_bounds__(256) void trans_wa_kernel(const float* __restrict__ W,
                                                       u16* __restrict__ wta) {
  __shared__ u16 T[64][72];
  const int n0 = blockIdx.x * 64;
  const int k0 = blockIdx.y * 64;
  const int tid = threadIdx.x;
  const int r = tid >> 4, c4 = (tid & 15) * 4;
#pragma unroll
  for (int i = 0; i < 4; i++) {
    int row = r + i * 16;
    float4 v = *(const float4*)&W[(size_t)(k0 + row) * 1536 + n0 + c4];
    T[c4 + 0][row] = f2bf(v.x);
    T[c4 + 1][row] = f2bf(v.y);
    T[c4 + 2][row] = f2bf(v.z);
    T[c4 + 3][row] = f2bf(v.w);
  }
  __syncthreads();
  const int row = tid >> 2, c16 = (tid & 3) * 16;
  *(uint4*)&wta[(size_t)(n0 + row) * 512 + k0 + c16]     = *(uint4*)&T[row][c16];
  *(uint4*)&wta[(size_t)(n0 + row) * 512 + k0 + c16 + 8] = *(uint4*)&T[row][c16 + 8];
}

// W_out [512][512] -> wcat [512][1536] = [Wh | Wl | Wh] (B^T layout)
__global__ __launch_bounds__(256) void trans_wo_kernel(const float* __restrict__ W,
                                                       u16* __restrict__ wcat) {
  __shared__ u16 Th[64][72];
  __shared__ u16 Tl[64][72];
  const int n0 = blockIdx.x * 64;
  const int k0 = blockIdx.y * 64;
  const int tid = threadIdx.x;
  const int r = tid >> 4, c4 = (tid & 15) * 4;
#pragma unroll
  for (int i = 0; i < 4; i++) {
    int row = r + i * 16;
    float4 v = *(const float4*)&W[(size_t)(k0 + row) * 512 + n0 + c4];
    float vv[4] = {v.x, v.y, v.z, v.w};
#pragma unroll
    for (int jj = 0; jj < 4; jj++) {
      u16 hi = f2bf(vv[jj]);
      Th[c4 + jj][row] = hi;
      Tl[c4 + jj][row] = f2bf(vv[jj] - bf2f(hi));
    }
  }
  __syncthreads();
  const int row = tid >> 2, c16 = (tid & 3) * 16;
  size_t base = (size_t)(n0 + row) * 1536 + k0 + c16;
  *(uint4*)&wcat[base]            = *(uint4*)&Th[row][c16];
  *(uint4*)&wcat[base + 8]        = *(uint4*)&Th[row][c16 + 8];
  *(uint4*)&wcat[base + 512]      = *(uint4*)&Tl[row][c16];
  *(uint4*)&wcat[base + 512 + 8]  = *(uint4*)&Tl[row][c16 + 8];
  *(uint4*)&wcat[base + 1024]     = *(uint4*)&Th[row][c16];
  *(uint4*)&wcat[base + 1024 + 8] = *(uint4*)&Th[row][c16 + 8];
}

// ---------------- QKV GEMM (m97-style 128x128, global_load_lds) ----------
// Q: scaled by 0.125*log2(e), [bh][t][64]; K: [bh][t][64]
// V: frag-packed V'[bh][it][ks][d][quad][jj]
__global__ __launch_bounds__(256) void gemm_qkv(const u16* __restrict__ xb,
                                                const u16* __restrict__ wta,
                                                const float* __restrict__ b_attn,
                                                u16* __restrict__ q,
                                                u16* __restrict__ kk,
                                                u16* __restrict__ v) {
  __shared__ u16 A_lds[128 * 64];
  __shared__ u16 B_lds[128 * 64];
  const int n0 = blockIdx.x * 128;
  const int m0 = blockIdx.y * 128;
  const int tid  = threadIdx.x;
  const int lane = tid & 63, w = tid >> 6;
  const int wm = w >> 1, wn = w & 1;
  const int quad = lane >> 4, l15 = lane & 15;

  f32x4 acc[4][4] = {};

  for (int k0 = 0; k0 < 512; k0 += 64) {
    stage_tile(xb  + (size_t)m0 * 512 + k0, 512, A_lds, tid);
    stage_tile(wta + (size_t)n0 * 512 + k0, 512, B_lds, tid);
    __syncthreads();
#pragma unroll
    for (int ks = 0; ks < 2; ks++) {
      bf16x8 af[4], bf[4];
#pragma unroll
      for (int ri = 0; ri < 4; ri++)
        af[ri] = *(const bf16x8*)&A_lds[(wm * 64 + ri * 16 + l15) * 64 + ks * 32 + quad * 8];
#pragma unroll
      for (int ci = 0; ci < 4; ci++)
        bf[ci] = *(const bf16x8*)&B_lds[(wn * 64 + ci * 16 + l15) * 64 + ks * 32 + quad * 8];
#pragma unroll
      for (int ri = 0; ri < 4; ri++)
#pragma unroll
        for (int ci = 0; ci < 4; ci++)
          acc[ri][ci] = MFMA16(af[ri], bf[ci], acc[ri][ci]);
    }
    __syncthreads();
  }

  const float QS = 0.18033688011112043f;  // 0.125 * log2(e)
#pragma unroll
  for (int ri = 0; ri < 4; ri++) {
#pragma unroll
    for (int ci = 0; ci < 4; ci++) {
      int n = n0 + wn * 64 + ci * 16 + l15;
      float bias = b_attn[n];
      int chunk = n >> 9;
      int c = n & 511;
      int h = c >> 6, d = c & 63;
      int m_base = m0 + wm * 64 + ri * 16 + quad * 4;
      int b = m_base >> 11, t0 = m_base & 2047;
      int bh = b * 8 + h;
      if (chunk == 0) {
#pragma unroll
        for (int r = 0; r < 4; r++)
          q[(size_t)(bh * 2048 + t0 + r) * 64 + d] = f2bf((acc[ri][ci][r] + bias) * QS);
      } else if (chunk == 1) {
#pragma unroll
        for (int r = 0; r < 4; r++)
          kk[(size_t)(bh * 2048 + t0 + r) * 64 + d] = f2bf(acc[ri][ci][r] + bias);
      } else {
        int it = t0 >> 7, ks2 = (t0 >> 5) & 3, qd = (t0 >> 3) & 3, jj = t0 & 7;
        ushort4 pk;
        pk.x = f2bf(acc[ri][ci][0] + bias);
        pk.y = f2bf(acc[ri][ci][1] + bias);
        pk.z = f2bf(acc[ri][ci][2] + bias);
        pk.w = f2bf(acc[ri][ci][3] + bias);
        size_t idx = ((((size_t)bh * 16 + it) * 4 + ks2) * 64 + d) * 32 + qd * 8 + jj;
        *(ushort4*)&v[idx] = pk;
      }
    }
  }
}

// ---------------- flash attention ----------------
// grid 512 (XCD-swizzled), 4 waves, wave = 32 q rows, 128-wide KV tiles.
// K double-buffered via global_load_lds (no VGPR staging, loads in flight
// through the whole compute phase before the barrier drain).
__global__ __launch_bounds__(256, 2) void flash_attn(const u16* __restrict__ q,
                                                     const u16* __restrict__ k,
                                                     const u16* __restrict__ vt,
                                                     u16* __restrict__ yb) {
  __shared__ u16 K_lds[2][128 * 64];   // contiguous (global_load_lds layout)
  __shared__ u16 P_lds[4 * 32 * 136];  // per-wave [32 q][128 j +pad]

  const int flat = blockIdx.y * 16 + blockIdx.x;
  const int bh = (flat & 7) * 4 + ((flat >> 3) & 3);
  const int qt = flat >> 5;

  const int tid  = threadIdx.x;
  const int lane = tid & 63, w = tid >> 6;
  const int quad = lane >> 4, l15 = lane & 15;

  const u16* qp = q  + (size_t)bh * 131072;
  const u16* kp = k  + (size_t)bh * 131072;
  const u16* vp = vt + (size_t)bh * 131072;

  bf16x8 qf[2][2];
#pragma unroll
  for (int qh = 0; qh < 2; qh++)
#pragma unroll
    for (int ks = 0; ks < 2; ks++)
      qf[qh][ks] = *(const bf16x8*)(qp + (size_t)(qt * 128 + w * 32 + qh * 16 + l15) * 64 + ks * 32 + quad * 8);

  f32x4 l_acc[2] = {};
  f32x4 o[2][4] = {};

  bf16x8 ones;
  {
    short one = (short)0x3F80;
    ones = (bf16x8){one, one, one, one, one, one, one, one};
  }

  u16* Pw = &P_lds[w * 32 * 136];

  stage_tile(kp, 64, K_lds[0], tid);   // tile 0

  for (int it = 0; it < 16; it++) {
    __syncthreads();   // drains vmcnt: staged loads had full prev compute in flight
    if (it < 15) stage_tile(kp + (size_t)(it + 1) * 8192, 64, K_lds[(it + 1) & 1], tid);
    const u16* Kb = K_lds[it & 1];

    const u16* vit = vp + it * 8192;
    bf16x8 vf[2][4];
#pragma unroll
    for (int dt = 0; dt < 4; dt++)
      vf[0][dt] = *(const bf16x8*)(vit + (dt * 16 + l15) * 32 + quad * 8);

    // S^T streamed over jt: MFMA -> exp2 -> pack -> P write
#pragma unroll
    for (int jt = 0; jt < 8; jt++) {
      f32x4 s0 = {0.f, 0.f, 0.f, 0.f}, s1 = {0.f, 0.f, 0.f, 0.f};
#pragma unroll
      for (int ks = 0; ks < 2; ks++) {
        bf16x8 kf = *(const bf16x8*)&Kb[(jt * 16 + l15) * 64 + ks * 32 + quad * 8];
        s0 = MFMA16(kf, qf[0][ks], s0);
        s1 = MFMA16(kf, qf[1][ks], s1);
      }
      u32 pb[4];
#pragma unroll
      for (int r = 0; r < 4; r++) pb[r] = __float_as_uint(EXP2(s0[r]));
      uint2 pk0;
      pk0.x = __builtin_amdgcn_perm(pb[1], pb[0], 0x07060302u);
      pk0.y = __builtin_amdgcn_perm(pb[3], pb[2], 0x07060302u);
      *(uint2*)&Pw[l15 * 136 + jt * 16 + quad * 4] = pk0;
#pragma unroll
      for (int r = 0; r < 4; r++) pb[r] = __float_as_uint(EXP2(s1[r]));
      uint2 pk1;
      pk1.x = __builtin_amdgcn_perm(pb[1], pb[0], 0x07060302u);
      pk1.y = __builtin_amdgcn_perm(pb[3], pb[2], 0x07060302u);
      *(uint2*)&Pw[(16 + l15) * 136 + jt * 16 + quad * 4] = pk1;
    }

    // O += P·V ; l += P·1
#pragma unroll
    for (int ks = 0; ks < 4; ks++) {
      if (ks < 3) {
#pragma unroll
        for (int dt = 0; dt < 4; dt++)
          vf[(ks + 1) & 1][dt] = *(const bf16x8*)(vit + (ks + 1) * 2048 + (dt * 16 + l15) * 32 + quad * 8);
      }
      bf16x8 pf0 = *(const bf16x8*)&Pw[l15 * 136 + ks * 32 + quad * 8];
      bf16x8 pf1 = *(const bf16x8*)&Pw[(16 + l15) * 136 + ks * 32 + quad * 8];
      l_acc[0] = MFMA16(pf0, ones, l_acc[0]);
      l_acc[1] = MFMA16(pf1, ones, l_acc[1]);
#pragma unroll
      for (int dt = 0; dt < 4; dt++) {
        o[0][dt] = MFMA16(pf0, vf[ks & 1][dt], o[0][dt]);
        o[1][dt] = MFMA16(pf1, vf[ks & 1][dt], o[1][dt]);
      }
    }
  }

  // epilogue: normalize, transpose via LDS, write y_cat[8192][1536] = [hi|hi|lo]
  const int b = bh >> 3, h = bh & 7;
  u32* Tw = (u32*)Pw;
#pragma unroll
  for (int qh = 0; qh < 2; qh++) {
#pragma unroll
    for (int r = 0; r < 4; r++) {
      float inv = 1.f / l_acc[qh][r];
#pragma unroll
      for (int dt = 0; dt < 4; dt++) {
        float val = o[qh][dt][r] * inv;
        u16 hi = f2bf(val);
        u16 lo = f2bf(val - bf2f(hi));
        Tw[(quad * 4 + r) * 68 + dt * 16 + l15] = (u32)hi | ((u32)lo << 16);
      }
    }
    int t = qt * 128 + w * 32 + qh * 16 + l15;
    size_t rowb = (size_t)(b * 2048 + t) * 1536 + h * 64 + quad * 16;
#pragma unroll
    for (int half = 0; half < 2; half++) {
      uint4 ga = *(uint4*)&Tw[l15 * 68 + quad * 16 + half * 8 + 0];
      uint4 gb = *(uint4*)&Tw[l15 * 68 + quad * 16 + half * 8 + 4];
      uint4 hi4, lo4;
      hi4.x = __builtin_amdgcn_perm(ga.y, ga.x, 0x05040100u);
      hi4.y = __builtin_amdgcn_perm(ga.w, ga.z, 0x05040100u);
      hi4.z = __builtin_amdgcn_perm(gb.y, gb.x, 0x05040100u);
      hi4.w = __builtin_amdgcn_perm(gb.w, gb.z, 0x05040100u);
      lo4.x = __builtin_amdgcn_perm(ga.y, ga.x, 0x07060302u);
      lo4.y = __builtin_amdgcn_perm(ga.w, ga.z, 0x07060302u);
      lo4.z = __builtin_amdgcn_perm(gb.y, gb.x, 0x07060302u);
      lo4.w = __builtin_amdgcn_perm(gb.w, gb.z, 0x07060302u);
      *(uint4*)&yb[rowb + half * 8]        = hi4;   // hi (pairs with Wh)
      *(uint4*)&yb[rowb + half * 8 + 512]  = hi4;   // hi (pairs with Wl)
      *(uint4*)&yb[rowb + half * 8 + 1024] = lo4;   // lo (pairs with Wh)
    }
  }
}

// ---------------- output projection: plain K=1536 GEMM over y_cat/wcat ----
__global__ __launch_bounds__(256) void gemm_out(const u16* __restrict__ ycat,
                                                const u16* __restrict__ wcat,
                                                const float* __restrict__ b_out,
                                                float* __restrict__ out) {
  __shared__ u16 A_lds[128 * 64];
  __shared__ u16 B_lds[128 * 64];
  const int n0 = blockIdx.x * 128;
  const int m0 = blockIdx.y * 128;
  const int tid  = threadIdx.x;
  const int lane = tid & 63, w = tid >> 6;
  const int wm = w >> 1, wn = w & 1;
  const int quad = lane >> 4, l15 = lane & 15;

  f32x4 acc[4][4] = {};

  for (int k0 = 0; k0 < 1536; k0 += 64) {
    stage_tile(ycat + (size_t)m0 * 1536 + k0, 1536, A_lds, tid);
    stage_tile(wcat + (size_t)n0 * 1536 + k0, 1536, B_lds, tid);
    __syncthreads();
#pragma unroll
    for (int ks = 0; ks < 2; ks++) {
      bf16x8 af[4], bf[4];
#pragma unroll
      for (int ri = 0; ri < 4; ri++)
        af[ri] = *(const bf16x8*)&A_lds[(wm * 64 + ri * 16 + l15) * 64 + ks * 32 + quad * 8];
#pragma unroll
      for (int ci = 0; ci < 4; ci++)
        bf[ci] = *(const bf16x8*)&B_lds[(wn * 64 + ci * 16 + l15) * 64 + ks * 32 + quad * 8];
#pragma unroll
      for (int ri = 0; ri < 4; ri++)
#pragma unroll
        for (int ci = 0; ci < 4; ci++)
          acc[ri][ci] = MFMA16(af[ri], bf[ci], acc[ri][ci]);
    }
    __syncthreads();
  }

#pragma unroll
  for (int ri = 0; ri < 4; ri++) {
#pragma unroll
    for (int ci = 0; ci < 4; ci++) {
      int n = n0 + wn * 64 + ci * 16 + l15;
      float bias = b_out[n];
#pragma unroll
      for (int r = 0; r < 4; r++) {
        int m = m0 + wm * 64 + ri * 16 + quad * 4 + r;
        out[(size_t)m * 512 + n] = acc[ri][ci][r] + bias;
      }
    }
  }
}

// ---------------- launch ----------------
extern "C" void kernel_launch(void* const* d_in, const int* in_sizes, int n_in,
                              void* d_out, int out_size, void* d_ws, size_t ws_size,
                              hipStream_t stream) {
  const float* x      = (const float*)d_in[0];
  const float* W_attn = (const float*)d_in[1];
  const float* b_attn = (const float*)d_in[2];
  const float* W_out  = (const float*)d_in[3];
  const float* b_out  = (const float*)d_in[4];
  float* out = (float*)d_out;

  char* ws = (char*)d_ws;
  // y_cat [0, 24MB) aliases xb+wta (both dead before flash writes y_cat)
  u16* ycat = (u16*)(ws + 0);                 // 24 MB [8192][1536]
  u16* xb   = (u16*)(ws + 0);                 //  8 MB [8192][512]   (dead after gemm_qkv)
  u16* wta  = (u16*)(ws + 8388608);           // 1.5 MB [1536][512]  (dead after gemm_qkv)
  u16* wcat = (u16*)(ws + 25165824);          // 1.5 MB [512][1536]
  u16* qb   = (u16*)(ws + 26738688);          //  8 MB [bh][t][64] (pre-scaled)
  u16* kb   = (u16*)(ws + 35127296);          //  8 MB [bh][t][64]
  u16* vtb  = (u16*)(ws + 43515904);          //  8 MB V' frag-packed

  cast_x_kernel<<<4096, 256, 0, stream>>>(x, xb, 4 * 2048 * 512 / 4);
  trans_wa_kernel<<<dim3(24, 8), 256, 0, stream>>>(W_attn, wta);
  trans_wo_kernel<<<dim3(8, 8), 256, 0, stream>>>(W_out, wcat);
  gemm_qkv<<<dim3(12, 64), 256, 0, stream>>>(xb, wta, b_attn, qb, kb, vtb);
  flash_attn<<<dim3(16, 32), 256, 0, stream>>>(qb, kb, vtb, ycat);
  gemm_out<<<dim3(4, 64), 256, 0, stream>>>(ycat, wcat, b_out, out);
}